// Round 8
// baseline (630.401 us; speedup 1.0000x reference)
//
#include <hip/hip_runtime.h>
#include <hip/hip_bf16.h>

// Qriaffine: out[n,i,j] = sum_{a,b,c,d} l1[n,i,a] W[a,b,c,d] l2[n,j,b] h1[n,i,c] h2[n,j,d]
// Plan:
//   P[(n,i)][(a*65+c)] = l1[a]*h1[c]        (8192 x 4225, bf16, pad K->4288)
//   Wt2[(b*65+d)][(a*65+c)] = W[a,b,c,d]    (4225 x 4225, bf16, pad -> 4352 x 4288)
//   Q = P @ Wt2 (NT gemm)                   (8192 x 4352, bf16)
//   R[(n,j)][(b*65+d)] = l2[b]*h2[d]        (8192 x 4352, bf16, built AFTER gemm1)
//   out_n = Q_n @ R_n^T (NT gemm, f32 out)  (8 x 1024 x 1024)
//
// R10: gemm1 ported to the m201-style 8-phase/counted-vmcnt schedule at
// 256x256, derived from first principles with a fully closed ledger:
//   - 8 waves (2Mx4N), per-wave 128x64 out (acc 4x2 of 32x32 = 128 regs),
//     2 waves/SIMD regime, LDS 128KiB = 2 bufs x 2 halves x (A,B) 128x64.
//   - per K-tile, 4 phases {reads; stage 1 half; barrier; lgkm0; 8 MFMA;
//     barrier}: p0 reads B-frags+A-strips0,1 & stages B1(t+1)->buf^1;
//     p1 reads strips2,3 & stages B0(t+2)->buf; p2/p3 stage A0/A1(t+2).
//     Per-half WAR is legal: each half's reads end >=1 barrier before its
//     overwrite (B at p0, A at p1).
//   - vmcnt(6) ONCE per K-tile at p3 before the barrier: each wave drains
//     its own older stages -> after barrier, tile t+1 globally resident;
//     3 halves (6 loads) stay in flight across barriers (T4). Tail tiles
//     (t>=NT-2) use vmcnt(0). Prologue = 7 halves + vmcnt(6) = exactly the
//     steady-state invariant.
//   - T5 setprio around each MFMA strip (8-phase = its proven regime).
//   - Fragment/swizzle/staging code identical to the verified R3 kernel
//     (rows are 128B in both; sg = sl^(row&7)).
// Tail (zero_pad, build_wt2, build_p 4-row, gemm2 SWZ=2) = R8's measured
// best config, byte-identical.

typedef __attribute__((ext_vector_type(8))) short short8;     // 8 bf16 = 4 VGPRs
typedef __attribute__((ext_vector_type(16))) float floatx16;  // MFMA 32x32 acc

#define KP 4288   // padded (a,c) dim: 67*64
#define DP 4352   // padded (b,d) dim: 68*64 = 34*128 = 17*256
#define NROW 8192 // n*L

__device__ __forceinline__ void async_ld16(const void* g, void* l) {
  __builtin_amdgcn_global_load_lds(
      (const __attribute__((address_space(1))) unsigned int*)g,
      (__attribute__((address_space(3))) unsigned int*)l, 16, 0, 0);
}

// ---------------- pad-only zero for Wt2 ----------------
__global__ void zero_pad_wt2(__hip_bfloat16* __restrict__ Wt2) {
  const int ROWPAD = 127 * KP;    // rows 4225..4351 full width
  const int COLPAD = 4225 * 63;   // rows 0..4224, cols 4225..4287
  const int total = ROWPAD + COLPAD;
  const __hip_bfloat16 z = __float2bfloat16(0.f);
  for (int id = blockIdx.x * 256 + threadIdx.x; id < total;
       id += gridDim.x * 256) {
    if (id < ROWPAD) {
      int row = 4225 + id / KP, col = id % KP;
      Wt2[(size_t)row * KP + col] = z;
    } else {
      int j = id - ROWPAD;
      int row = j / 63, col = 4225 + j % 63;
      Wt2[(size_t)row * KP + col] = z;
    }
  }
}

// ---------------- W[a,b,c,d] -> Wt2[(b*65+d)][(a*65+c)] (bf16) ----------------
__global__ void build_wt2(const float* __restrict__ W, __hip_bfloat16* __restrict__ Wt2) {
  __shared__ __hip_bfloat16 tile[65 * 66];
  const int a = blockIdx.x, b = blockIdx.y;
  const float* src = W + (size_t)(a * 65 + b) * 4225;  // contiguous (c,d) plane
  for (int idx = threadIdx.x; idx < 4225; idx += 256) {
    int c = idx / 65, d = idx - c * 65;
    tile[d * 66 + c] = __float2bfloat16(src[idx]);
  }
  __syncthreads();
  for (int idx = threadIdx.x; idx < 4225; idx += 256) {
    int d = idx / 65, c = idx - d * 65;
    Wt2[(size_t)(b * 65 + d) * KP + a * 65 + c] = tile[d * 66 + c];
  }
}

// ---------------- P/R builder: P[row][x*65+y] = layer_row[x] * h_row[y] ----------------
__global__ void build_p(const float* __restrict__ layer, const float* __restrict__ h,
                        __hip_bfloat16* __restrict__ P, int width) {
  const int row0 = blockIdx.x * 4;
  __shared__ float lv[4][65], hv[4][65];
  for (int i = threadIdx.x; i < 260; i += 256) {
    int rr = i / 65, x = i - rr * 65;
    lv[rr][x] = (x < 64) ? layer[(size_t)(row0 + rr) * 64 + x] : 1.0f;
    hv[rr][x] = h[(size_t)(row0 + rr) * 65 + x];
  }
  __syncthreads();
#pragma unroll
  for (int rr = 0; rr < 4; ++rr) {
    const size_t rowbase = (size_t)(row0 + rr) * width;
    for (int base = threadIdx.x * 8; base < width; base += 256 * 8) {
      alignas(16) __hip_bfloat16 tmp[8];
#pragma unroll
      for (int j = 0; j < 8; ++j) {
        int idx = base + j;
        float v = 0.f;
        if (idx < 4225) {
          int x = idx / 65, y = idx - x * 65;
          v = lv[rr][x] * hv[rr][y];
        }
        tmp[j] = __float2bfloat16(v);
      }
      *(float4*)(P + rowbase + base) = *(const float4*)tmp;
    }
  }
}

// ---------------- gemm1: 256x256 NT GEMM, 8-phase counted-vmcnt, bf16 out ----------------
// C[i][j] = sum_k A[i][k]*B[j][k]. Grid must be exactly (DP/256, NROW/256).
#define SBAR __builtin_amdgcn_sched_barrier(0)

__global__ __launch_bounds__(512) void gemm1_8p(
    const __hip_bfloat16* __restrict__ A, const __hip_bfloat16* __restrict__ B,
    __hip_bfloat16* __restrict__ C, int K, int lda, int ldb, int ldc) {
  __shared__ alignas(16) __hip_bfloat16 As[2][2][128 * 64];
  __shared__ alignas(16) __hip_bfloat16 Bs[2][2][128 * 64];
  // XCD remap: grid (17,32) -> 544 = 8*68; XCD k owns by in [4k,4k+4).
  const int orig = blockIdx.x + 17 * blockIdx.y;
  const int xcd = orig & 7;
  const int idx = orig >> 3;              // 0..67
  const int by = (xcd << 2) + idx / 17;
  const int bx = idx % 17;
  const int bm = by * 256, bn = bx * 256;

  const int t = threadIdx.x;
  const int lane = t & 63, w = t >> 6;    // 8 waves
  const int l31 = lane & 31, lhi = lane >> 5, x7 = l31 & 7;
  const int ah = w >> 2;                  // A half (M): 0/1
  const int wm = ah * 128;
  const int wn = (w & 3) * 64;            // N offset 0..192
  const int bh = (w & 3) >> 1;            // B half (N): 0/1
  const int wnin = wn & 127;              // N offset within half

  // fragment offsets within a [128][64] half (elements)
  int co[4];
#pragma unroll
  for (int ks = 0; ks < 4; ++ks) co[ks] = ((ks * 2 + lhi) ^ x7) * 8;
  const int ab = l31 * 64;                          // A strip base (+= mf*2048)
  const int bb0 = (wnin + l31) * 64;                // B nf=0
  const int bb1 = (wnin + 32 + l31) * 64;           // B nf=1

  // staging: half = 1024 chunks of 16B; thread handles L = r*512+t, r=0,1.
  // srow = L>>3, sl = L&7, src chunk sg = sl^(srow&7); LDS dest linear.
  const int srow = t >> 3;
  const int sg = (t & 7) ^ (srow & 7);    // same for r=0,1 (srow+64 keeps &7... (64+srow)&7==srow&7? 64%8==0 -> yes)
  const __hip_bfloat16* gA0 = A + (size_t)(bm + srow) * lda + sg * 8;
  const __hip_bfloat16* gA1 = A + (size_t)(bm + 64 + srow) * lda + sg * 8;
  const __hip_bfloat16* gB0 = B + (size_t)(bn + srow) * ldb + sg * 8;
  const __hip_bfloat16* gB1 = B + (size_t)(bn + 64 + srow) * ldb + sg * 8;
  const int st0 = w * 512;                // LDS elem offset, r=0 (wave-uniform)
  const int st1 = 4096 + w * 512;         // r=1

#define STAGE_AH(kt, h)                                                        \
  do {                                                                         \
    const int _c = (kt) & 1;                                                   \
    const size_t _hk = (size_t)(h) * 128 * lda + (size_t)(kt) * 64;            \
    async_ld16(gA0 + _hk, &As[_c][h][st0]);                                    \
    async_ld16(gA1 + _hk, &As[_c][h][st1]);                                    \
  } while (0)
#define STAGE_BH(kt, h)                                                        \
  do {                                                                         \
    const int _c = (kt) & 1;                                                   \
    const size_t _hk = (size_t)(h) * 128 * ldb + (size_t)(kt) * 64;            \
    async_ld16(gB0 + _hk, &Bs[_c][h][st0]);                                    \
    async_ld16(gB1 + _hk, &Bs[_c][h][st1]);                                    \
  } while (0)

  const int NT = K >> 6;  // 67

  // ---- prologue: tile0 all 4 halves + tile1 {B0,A0,A1} (B1(1) staged at t=0 p0)
  STAGE_BH(0, 0); STAGE_BH(0, 1); STAGE_AH(0, 0); STAGE_AH(0, 1);
  STAGE_BH(1, 0); STAGE_AH(1, 0); STAGE_AH(1, 1);
  SBAR;
  asm volatile("s_waitcnt vmcnt(6)\n\ts_barrier" ::: "memory");  // tile0 resident

  floatx16 acc[4][2] = {};

  for (int kt = 0; kt < NT; ++kt) {
    const int c = kt & 1;
    const __hip_bfloat16* Ah = &As[c][ah][0];
    const __hip_bfloat16* Bh = &Bs[c][bh][0];
    short8 bf[2][4], a0[4], a1[4], a2[4], a3[4];

    // ---- phase 0: read B-frags + A strips 0,1; stage B1(kt+1) -> buf c^1
#pragma unroll
    for (int ks = 0; ks < 4; ++ks) {
      bf[0][ks] = *(const short8*)(Bh + bb0 + co[ks]);
      bf[1][ks] = *(const short8*)(Bh + bb1 + co[ks]);
      a0[ks] = *(const short8*)(Ah + ab + co[ks]);
      a1[ks] = *(const short8*)(Ah + 2048 + ab + co[ks]);
    }
    if (kt + 1 < NT) STAGE_BH(kt + 1, 1);
    SBAR;
    asm volatile("s_barrier\n\ts_waitcnt lgkmcnt(0)" ::: "memory");
    SBAR;
    __builtin_amdgcn_s_setprio(1);
#pragma unroll
    for (int ks = 0; ks < 4; ++ks) {
      acc[0][0] = __builtin_amdgcn_mfma_f32_32x32x16_bf16(a0[ks], bf[0][ks], acc[0][0], 0, 0, 0);
      acc[0][1] = __builtin_amdgcn_mfma_f32_32x32x16_bf16(a0[ks], bf[1][ks], acc[0][1], 0, 0, 0);
    }
    __builtin_amdgcn_s_setprio(0);
    SBAR;
    asm volatile("s_barrier" ::: "memory");

    // ---- phase 1: read A strips 2,3; stage B0(kt+2) -> buf c
#pragma unroll
    for (int ks = 0; ks < 4; ++ks) {
      a2[ks] = *(const short8*)(Ah + 2 * 2048 + ab + co[ks]);
      a3[ks] = *(const short8*)(Ah + 3 * 2048 + ab + co[ks]);
    }
    if (kt + 2 < NT) STAGE_BH(kt + 2, 0);
    SBAR;
    asm volatile("s_barrier\n\ts_waitcnt lgkmcnt(0)" ::: "memory");
    SBAR;
    __builtin_amdgcn_s_setprio(1);
#pragma unroll
    for (int ks = 0; ks < 4; ++ks) {
      acc[1][0] = __builtin_amdgcn_mfma_f32_32x32x16_bf16(a1[ks], bf[0][ks], acc[1][0], 0, 0, 0);
      acc[1][1] = __builtin_amdgcn_mfma_f32_32x32x16_bf16(a1[ks], bf[1][ks], acc[1][1], 0, 0, 0);
    }
    __builtin_amdgcn_s_setprio(0);
    SBAR;
    asm volatile("s_barrier" ::: "memory");

    // ---- phase 2: stage A0(kt+2) -> buf c (its reads ended at p1)
    if (kt + 2 < NT) STAGE_AH(kt + 2, 0);
    SBAR;
    asm volatile("s_barrier" ::: "memory");
    SBAR;
    __builtin_amdgcn_s_setprio(1);
#pragma unroll
    for (int ks = 0; ks < 4; ++ks) {
      acc[2][0] = __builtin_amdgcn_mfma_f32_32x32x16_bf16(a2[ks], bf[0][ks], acc[2][0], 0, 0, 0);
      acc[2][1] = __builtin_amdgcn_mfma_f32_32x32x16_bf16(a2[ks], bf[1][ks], acc[2][1], 0, 0, 0);
    }
    __builtin_amdgcn_s_setprio(0);
    SBAR;
    asm volatile("s_barrier" ::: "memory");

    // ---- phase 3: stage A1(kt+2); counted vmcnt -> tile kt+1 resident
    if (kt + 2 < NT) STAGE_AH(kt + 2, 1);
    SBAR;
    if (kt < NT - 2)
      asm volatile("s_waitcnt vmcnt(6)\n\ts_barrier" ::: "memory");
    else
      asm volatile("s_waitcnt vmcnt(0)\n\ts_barrier" ::: "memory");
    SBAR;
    __builtin_amdgcn_s_setprio(1);
#pragma unroll
    for (int ks = 0; ks < 4; ++ks) {
      acc[3][0] = __builtin_amdgcn_mfma_f32_32x32x16_bf16(a3[ks], bf[0][ks], acc[3][0], 0, 0, 0);
      acc[3][1] = __builtin_amdgcn_mfma_f32_32x32x16_bf16(a3[ks], bf[1][ks], acc[3][1], 0, 0, 0);
    }
    __builtin_amdgcn_s_setprio(0);
    SBAR;
    asm volatile("s_barrier" ::: "memory");
  }

  // C/D layout (verified m74/m101): col = lane&31,
  // row = (reg&3) + 8*(reg>>2) + 4*(lane>>5)
#pragma unroll
  for (int mf = 0; mf < 4; ++mf)
#pragma unroll
    for (int nf = 0; nf < 2; ++nf)
#pragma unroll
      for (int reg = 0; reg < 16; ++reg) {
        int row = bm + wm + mf * 32 + (reg & 3) + 8 * (reg >> 2) + 4 * lhi;
        int col = bn + wn + nf * 32 + l31;
        C[(size_t)row * ldc + col] = __float2bfloat16(acc[mf][nf][reg]);
      }
#undef STAGE_AH
#undef STAGE_BH
}

// ---------------- NT GEMM (proven R3 kernel, used for gemm2) ----------------
// SWZ=2 (grid exactly (8,8,8)): batch-per-XCD remap (verified R8 config).
template <int STORE_BF16, int SWZ>
__global__ __launch_bounds__(256) void gemm_nt(
    const __hip_bfloat16* __restrict__ A, const __hip_bfloat16* __restrict__ B,
    void* __restrict__ Cv, int K, int lda, int ldb, int ldc,
    long sA, long sB, long sC) {
  __shared__ alignas(16) __hip_bfloat16 As[128 * 64];
  __shared__ alignas(16) __hip_bfloat16 Bs[128 * 64];
  int bx = blockIdx.x, by = blockIdx.y, z = blockIdx.z;
  if (SWZ == 2) {
    int orig = blockIdx.x + 8 * blockIdx.y + 64 * blockIdx.z;  // 0..511
    z = orig & 7;
    int r = orig >> 3;  // 0..63
    bx = r & 7;
    by = r >> 3;
  }
  A += (long)z * sA;
  B += (long)z * sB;
  const int bm = by * 128;
  const int bn = bx * 128;
  const int t = threadIdx.x;
  const int lane = t & 63;
  const int wave = t >> 6;
  const int l31 = lane & 31;
  const int lhi = lane >> 5;
  const int wm = (wave >> 1) * 64;
  const int wn = (wave & 1) * 64;

  const __hip_bfloat16* gA[4];
  const __hip_bfloat16* gB[4];
  __hip_bfloat16* lA[4];
  __hip_bfloat16* lB[4];
#pragma unroll
  for (int r = 0; r < 4; ++r) {
    int L = r * 256 + t;
    int row = L >> 3, sl = L & 7;
    int sg = sl ^ (row & 7);
    gA[r] = A + (size_t)(bm + row) * lda + sg * 8;
    gB[r] = B + (size_t)(bn + row) * ldb + sg * 8;
    lA[r] = As + (size_t)(r * 256 + wave * 64) * 8;
    lB[r] = Bs + (size_t)(r * 256 + wave * 64) * 8;
  }

  const int x7 = l31 & 7;
  const int rA0 = (wm + l31) * 64, rA1 = (wm + 32 + l31) * 64;
  const int rB0 = (wn + l31) * 64, rB1 = (wn + 32 + l31) * 64;

  floatx16 acc[2][2] = {};

  for (int k0 = 0; k0 < K; k0 += 64) {
    __syncthreads();
#pragma unroll
    for (int r = 0; r < 4; ++r) {
      async_ld16(gA[r] + k0, lA[r]);
      async_ld16(gB[r] + k0, lB[r]);
    }
    __syncthreads();

#pragma unroll
    for (int ks = 0; ks < 4; ++ks) {
      const int pc = ((ks * 2 + lhi) ^ x7) * 8;
      short8 a0 = *(const short8*)(&As[rA0 + pc]);
      short8 a1 = *(const short8*)(&As[rA1 + pc]);
      short8 b0 = *(const short8*)(&Bs[rB0 + pc]);
      short8 b1 = *(const short8*)(&Bs[rB1 + pc]);
      acc[0][0] = __builtin_amdgcn_mfma_f32_32x32x16_bf16(a0, b0, acc[0][0], 0, 0, 0);
      acc[0][1] = __builtin_amdgcn_mfma_f32_32x32x16_bf16(a0, b1, acc[0][1], 0, 0, 0);
      acc[1][0] = __builtin_amdgcn_mfma_f32_32x32x16_bf16(a1, b0, acc[1][0], 0, 0, 0);
      acc[1][1] = __builtin_amdgcn_mfma_f32_32x32x16_bf16(a1, b1, acc[1][1], 0, 0, 0);
    }
  }

  if (STORE_BF16) {
    __hip_bfloat16* C = (__hip_bfloat16*)Cv + (long)z * sC;
#pragma unroll
    for (int mt = 0; mt < 2; ++mt)
#pragma unroll
      for (int nt = 0; nt < 2; ++nt)
#pragma unroll
        for (int reg = 0; reg < 16; ++reg) {
          int row = bm + wm + mt * 32 + (reg & 3) + 8 * (reg >> 2) + 4 * lhi;
          int col = bn + wn + nt * 32 + l31;
          C[(size_t)row * ldc + col] = __float2bfloat16(acc[mt][nt][reg]);
        }
  } else {
    float* C = (float*)Cv + (long)z * sC;
#pragma unroll
    for (int mt = 0; mt < 2; ++mt)
#pragma unroll
      for (int nt = 0; nt < 2; ++nt)
#pragma unroll
        for (int reg = 0; reg < 16; ++reg) {
          int row = bm + wm + mt * 32 + (reg & 3) + 8 * (reg >> 2) + 4 * lhi;
          int col = bn + wn + nt * 32 + l31;
          C[(size_t)row * ldc + col] = acc[mt][nt][reg];
        }
  }
}

extern "C" void kernel_launch(void* const* d_in, const int* in_sizes, int n_in,
                              void* d_out, int out_size, void* d_ws, size_t ws_size,
                              hipStream_t stream) {
  const float* layer1 = (const float*)d_in[0];
  const float* layer2 = (const float*)d_in[1];
  const float* h1 = (const float*)d_in[3];
  const float* h2 = (const float*)d_in[4];
  const float* W = (const float*)d_in[6];
  float* out = (float*)d_out;

  // workspace layout (bytes), total high-water 178,880,512:
  //   [0 .. 70,254,592)            P  (8192*4288*2)   -- later reused for R
  //   [70,254,592 .. 107,577,344)  Wt2 (4352*4288*2)
  //   [107,577,344 .. 178,880,512) Q  (8192*4352*2)
  char* ws = (char*)d_ws;
  __hip_bfloat16* P = (__hip_bfloat16*)(ws);
  __hip_bfloat16* Wt2 = (__hip_bfloat16*)(ws + 70254592ULL);
  __hip_bfloat16* Q = (__hip_bfloat16*)(ws + 107577344ULL);
  __hip_bfloat16* R = (__hip_bfloat16*)(ws);  // reuses P/Wt2 region

  // 1) zero Wt2 pads only (real entries all overwritten by build_wt2)
  zero_pad_wt2<<<1024, 256, 0, stream>>>(Wt2);
  // 2) transpose+cast W
  build_wt2<<<dim3(65, 65), 256, 0, stream>>>(W, Wt2);
  // 3) P (4 rows per block)
  build_p<<<NROW / 4, 256, 0, stream>>>(layer1, h1, P, KP);
  // 4) Q = P @ Wt2 (NT): M=8192, N=4352, K=4288 — 8-phase 256^2 kernel
  gemm1_8p<<<dim3(DP / 256, NROW / 256), 512, 0, stream>>>(
      P, Wt2, Q, KP, KP, KP, DP);
  // 5) R (over the now-dead P/Wt2 region)
  build_p<<<NROW / 4, 256, 0, stream>>>(layer2, h2, R, DP);
  // 6) out_n = Q_n @ R_n^T: M=N=1024, K=4288 (cols 4225..4287 are zeros),
  //    batched over n=8, batch-per-XCD remap
  gemm_nt<0, 2><<<dim3(1024 / 128, 1024 / 128, 8), 256, 0, stream>>>(
      Q, R, out, 4288, DP, DP, 1024, 1024L * DP, 1024L * DP, 1024L * 1024);
}

// Round 9
// 581.038 us; speedup vs baseline: 1.0850x; 1.0850x over previous
//
#include <hip/hip_runtime.h>
#include <hip/hip_bf16.h>

// Qriaffine: out[n,i,j] = sum_{a,b,c,d} l1[n,i,a] W[a,b,c,d] l2[n,j,b] h1[n,i,c] h2[n,j,d]
// Plan:
//   P[(n,i)][(a*65+c)] = l1[a]*h1[c]        (8192 x 4225, bf16, pad K->4288)
//   Wt2[(b*65+d)][(a*65+c)] = W[a,b,c,d]    (4225 x 4225, bf16, pad -> 4352 x 4288)
//   Q = P @ Wt2 (NT gemm)                   (8192 x 4352, bf16)
//   R[(n,j)][(b*65+d)] = l2[b]*h2[d]        (8192 x 4352, bf16, built AFTER gemm1)
//   out_n = Q_n @ R_n^T (NT gemm, f32 out)  (8 x 1024 x 1024)
//
// R11: lock-in of the session-best R8 configuration (577.7us measured).
// Structural record, closed empirically across 5 variants:
//   R3 chassis (128x128, 4 waves, BK=64, 2-barrier) = 347us / 882 TF
//   R4 256x256 4-deep ring    620us | R5 2-wave 128x128     469us
//   R6 A-in-registers         704us | R10 8-phase cnt-vmcnt 419us (730 TF)
// Every deviation from the R3 structure lost; gemm1 is LOCKED. R10's
// post-mortem: 8 MFMA/barrier-pair = half the template's density -> phase
// overhead 2x; at 2 waves/SIMD no third wave absorbs it. The remaining
// gap to hipBLASLt-class (2026 TF) requires the full co-designed schedule,
// not reachable at one bench per round.
// Verified-win inventory kept here: XCD remap gemm1 (FETCH 643->272MB),
// batch-per-XCD remap gemm2, pad-only Wt2 zeroing, build_p 4-row,
// gemm2 K=4288 (zero cols trimmed).

typedef __attribute__((ext_vector_type(8))) short short8;     // 8 bf16 = 4 VGPRs
typedef __attribute__((ext_vector_type(16))) float floatx16;  // MFMA 32x32 acc

#define KP 4288   // padded (a,c) dim: 67*64
#define DP 4352   // padded (b,d) dim: 68*64 = 34*128
#define NROW 8192 // n*L

__device__ __forceinline__ void async_ld16(const void* g, void* l) {
  __builtin_amdgcn_global_load_lds(
      (const __attribute__((address_space(1))) unsigned int*)g,
      (__attribute__((address_space(3))) unsigned int*)l, 16, 0, 0);
}

// ---------------- pad-only zero for Wt2 ----------------
// real entries (rows 0..4224 x cols 0..4224) are all written by build_wt2;
// pads must be finite (0) so MFMA K-sums stay clean:
//   region A: rows 4225..4351 (127 rows), full KP width
//   region B: rows 0..4224, cols 4225..4287 (63 cols)
__global__ void zero_pad_wt2(__hip_bfloat16* __restrict__ Wt2) {
  const int ROWPAD = 127 * KP;    // 544,576
  const int COLPAD = 4225 * 63;   // 266,175
  const int total = ROWPAD + COLPAD;
  const __hip_bfloat16 z = __float2bfloat16(0.f);
  for (int id = blockIdx.x * 256 + threadIdx.x; id < total;
       id += gridDim.x * 256) {
    if (id < ROWPAD) {
      int row = 4225 + id / KP, col = id % KP;
      Wt2[(size_t)row * KP + col] = z;
    } else {
      int j = id - ROWPAD;
      int row = j / 63, col = 4225 + j % 63;
      Wt2[(size_t)row * KP + col] = z;
    }
  }
}

// ---------------- W[a,b,c,d] -> Wt2[(b*65+d)][(a*65+c)] (bf16) ----------------
__global__ void build_wt2(const float* __restrict__ W, __hip_bfloat16* __restrict__ Wt2) {
  __shared__ __hip_bfloat16 tile[65 * 66];
  const int a = blockIdx.x, b = blockIdx.y;
  const float* src = W + (size_t)(a * 65 + b) * 4225;  // contiguous (c,d) plane
  for (int idx = threadIdx.x; idx < 4225; idx += 256) {
    int c = idx / 65, d = idx - c * 65;
    tile[d * 66 + c] = __float2bfloat16(src[idx]);
  }
  __syncthreads();
  for (int idx = threadIdx.x; idx < 4225; idx += 256) {
    int d = idx / 65, c = idx - d * 65;
    Wt2[(size_t)(b * 65 + d) * KP + a * 65 + c] = tile[d * 66 + c];
  }
}

// ---------------- P/R builder: P[row][x*65+y] = layer_row[x] * h_row[y] ----------------
// 4 rows per block (grid = NROW/4) to amortize block setup.
__global__ void build_p(const float* __restrict__ layer, const float* __restrict__ h,
                        __hip_bfloat16* __restrict__ P, int width) {
  const int row0 = blockIdx.x * 4;
  __shared__ float lv[4][65], hv[4][65];
  for (int i = threadIdx.x; i < 260; i += 256) {
    int rr = i / 65, x = i - rr * 65;
    lv[rr][x] = (x < 64) ? layer[(size_t)(row0 + rr) * 64 + x] : 1.0f;
    hv[rr][x] = h[(size_t)(row0 + rr) * 65 + x];
  }
  __syncthreads();
#pragma unroll
  for (int rr = 0; rr < 4; ++rr) {
    const size_t rowbase = (size_t)(row0 + rr) * width;
    for (int base = threadIdx.x * 8; base < width; base += 256 * 8) {
      alignas(16) __hip_bfloat16 tmp[8];
#pragma unroll
      for (int j = 0; j < 8; ++j) {
        int idx = base + j;
        float v = 0.f;
        if (idx < 4225) {
          int x = idx / 65, y = idx - x * 65;
          v = lv[rr][x] * hv[rr][y];
        }
        tmp[j] = __float2bfloat16(v);
      }
      *(float4*)(P + rowbase + base) = *(const float4*)tmp;
    }
  }
}

// ---------------- NT GEMM (proven R3 kernel) ----------------
// A: M x K (lda), B: N x K (ldb), row-major bf16, K % 64 == 0.
// 128x128 block tile, 4 waves each 64x64 = 2x2 tiles of 32x32, BK=64,
// mfma_f32_32x32x16_bf16. Staging via global_load_lds x16, XOR-swizzled LDS.
// SWZ=1 (gemm1; grid exactly (34,64,1)): locality remap -- XCD k
// (linear-dispatch mod 8) owns M-rows [8k,8k+8); x swept in groups of 9.
// Bijective (verified R7: FETCH 643->272MB).
// SWZ=2 (gemm2; grid exactly (8,8,8)): batch-per-XCD remap -- XCD k owns
// batch z=k entirely (64 tiles); within, bx fastest so the by-row A-panel
// (1.1MB) stays L2-hot. orig = bx + 8*by + 64*bz; z'=orig&7,
// bx'=(orig>>3)&7, by'=orig>>6. Bijective.
template <int STORE_BF16, int SWZ>
__global__ __launch_bounds__(256) void gemm_nt(
    const __hip_bfloat16* __restrict__ A, const __hip_bfloat16* __restrict__ B,
    void* __restrict__ Cv, int K, int lda, int ldb, int ldc,
    long sA, long sB, long sC) {
  __shared__ alignas(16) __hip_bfloat16 As[128 * 64];
  __shared__ alignas(16) __hip_bfloat16 Bs[128 * 64];
  int bx = blockIdx.x, by = blockIdx.y, z = blockIdx.z;
  if (SWZ == 1) {
    int orig = blockIdx.x + 34 * blockIdx.y;  // grid (34,64) -> 0..2175
    int xcd = orig & 7;
    int idx = orig >> 3;                      // 0..271
    int xg = (idx < 216) ? (idx / 72) : 3;
    int r = idx - xg * 72;
    bx = xg * 9 + (r >> 3);
    by = (xcd << 3) + (r & 7);
  } else if (SWZ == 2) {
    int orig = blockIdx.x + 8 * blockIdx.y + 64 * blockIdx.z;  // 0..511
    z = orig & 7;
    int r = orig >> 3;  // 0..63
    bx = r & 7;
    by = r >> 3;
  }
  A += (long)z * sA;
  B += (long)z * sB;
  const int bm = by * 128;
  const int bn = bx * 128;
  const int t = threadIdx.x;
  const int lane = t & 63;
  const int wave = t >> 6;
  const int l31 = lane & 31;
  const int lhi = lane >> 5;
  const int wm = (wave >> 1) * 64;
  const int wn = (wave & 1) * 64;

  const __hip_bfloat16* gA[4];
  const __hip_bfloat16* gB[4];
  __hip_bfloat16* lA[4];
  __hip_bfloat16* lB[4];
#pragma unroll
  for (int r = 0; r < 4; ++r) {
    int L = r * 256 + t;
    int row = L >> 3, sl = L & 7;
    int sg = sl ^ (row & 7);
    gA[r] = A + (size_t)(bm + row) * lda + sg * 8;
    gB[r] = B + (size_t)(bn + row) * ldb + sg * 8;
    lA[r] = As + (size_t)(r * 256 + wave * 64) * 8;
    lB[r] = Bs + (size_t)(r * 256 + wave * 64) * 8;
  }

  const int x7 = l31 & 7;
  const int rA0 = (wm + l31) * 64, rA1 = (wm + 32 + l31) * 64;
  const int rB0 = (wn + l31) * 64, rB1 = (wn + 32 + l31) * 64;

  floatx16 acc[2][2] = {};

  for (int k0 = 0; k0 < K; k0 += 64) {
    __syncthreads();
#pragma unroll
    for (int r = 0; r < 4; ++r) {
      async_ld16(gA[r] + k0, lA[r]);
      async_ld16(gB[r] + k0, lB[r]);
    }
    __syncthreads();

#pragma unroll
    for (int ks = 0; ks < 4; ++ks) {
      const int pc = ((ks * 2 + lhi) ^ x7) * 8;
      short8 a0 = *(const short8*)(&As[rA0 + pc]);
      short8 a1 = *(const short8*)(&As[rA1 + pc]);
      short8 b0 = *(const short8*)(&Bs[rB0 + pc]);
      short8 b1 = *(const short8*)(&Bs[rB1 + pc]);
      acc[0][0] = __builtin_amdgcn_mfma_f32_32x32x16_bf16(a0, b0, acc[0][0], 0, 0, 0);
      acc[0][1] = __builtin_amdgcn_mfma_f32_32x32x16_bf16(a0, b1, acc[0][1], 0, 0, 0);
      acc[1][0] = __builtin_amdgcn_mfma_f32_32x32x16_bf16(a1, b0, acc[1][0], 0, 0, 0);
      acc[1][1] = __builtin_amdgcn_mfma_f32_32x32x16_bf16(a1, b1, acc[1][1], 0, 0, 0);
    }
  }

  // C/D layout (verified m74/m101): col = lane&31,
  // row = (reg&3) + 8*(reg>>2) + 4*(lane>>5)
  if (STORE_BF16) {
    __hip_bfloat16* C = (__hip_bfloat16*)Cv + (long)z * sC;
#pragma unroll
    for (int mt = 0; mt < 2; ++mt)
#pragma unroll
      for (int nt = 0; nt < 2; ++nt)
#pragma unroll
        for (int reg = 0; reg < 16; ++reg) {
          int row = bm + wm + mt * 32 + (reg & 3) + 8 * (reg >> 2) + 4 * lhi;
          int col = bn + wn + nt * 32 + l31;
          C[(size_t)row * ldc + col] = __float2bfloat16(acc[mt][nt][reg]);
        }
  } else {
    float* C = (float*)Cv + (long)z * sC;
#pragma unroll
    for (int mt = 0; mt < 2; ++mt)
#pragma unroll
      for (int nt = 0; nt < 2; ++nt)
#pragma unroll
        for (int reg = 0; reg < 16; ++reg) {
          int row = bm + wm + mt * 32 + (reg & 3) + 8 * (reg >> 2) + 4 * lhi;
          int col = bn + wn + nt * 32 + l31;
          C[(size_t)row * ldc + col] = acc[mt][nt][reg];
        }
  }
}

extern "C" void kernel_launch(void* const* d_in, const int* in_sizes, int n_in,
                              void* d_out, int out_size, void* d_ws, size_t ws_size,
                              hipStream_t stream) {
  const float* layer1 = (const float*)d_in[0];
  const float* layer2 = (const float*)d_in[1];
  const float* h1 = (const float*)d_in[3];
  const float* h2 = (const float*)d_in[4];
  const float* W = (const float*)d_in[6];
  float* out = (float*)d_out;

  // workspace layout (bytes), total high-water 178,880,512:
  //   [0 .. 70,254,592)            P  (8192*4288*2)   -- later reused for R
  //   [70,254,592 .. 107,577,344)  Wt2 (4352*4288*2)
  //   [107,577,344 .. 178,880,512) Q  (8192*4352*2)
  char* ws = (char*)d_ws;
  __hip_bfloat16* P = (__hip_bfloat16*)(ws);
  __hip_bfloat16* Wt2 = (__hip_bfloat16*)(ws + 70254592ULL);
  __hip_bfloat16* Q = (__hip_bfloat16*)(ws + 107577344ULL);
  __hip_bfloat16* R = (__hip_bfloat16*)(ws);  // reuses P/Wt2 region

  // 1) zero Wt2 pads only (real entries all overwritten by build_wt2)
  zero_pad_wt2<<<1024, 256, 0, stream>>>(Wt2);
  // 2) transpose+cast W
  build_wt2<<<dim3(65, 65), 256, 0, stream>>>(W, Wt2);
  // 3) P (4 rows per block)
  build_p<<<NROW / 4, 256, 0, stream>>>(layer1, h1, P, KP);
  // 4) Q = P @ Wt2 (NT): M=8192, N=4352, K=4288 — R3 kernel + locality remap
  gemm_nt<1, 1><<<dim3(DP / 128, NROW / 128, 1), 256, 0, stream>>>(
      P, Wt2, Q, KP, KP, KP, DP, 0, 0, 0);
  // 5) R (over the now-dead P/Wt2 region)
  build_p<<<NROW / 4, 256, 0, stream>>>(layer2, h2, R, DP);
  // 6) out_n = Q_n @ R_n^T: M=N=1024, K=4288 (cols 4225..4287 are zeros),
  //    batched over n=8, batch-per-XCD remap
  gemm_nt<0, 2><<<dim3(1024 / 128, 1024 / 128, 8), 256, 0, stream>>>(
      Q, R, out, 4288, DP, DP, 1024, 1024L * DP, 1024L * DP, 1024L * 1024);
}